// Round 1
// 58.837 us; speedup vs baseline: 1.0435x; 1.0435x over previous
//
#include <hip/hip_runtime.h>

#define T_LEN 1024

// Fused single kernel. out[r][n] = sum_s u[r][1023-s] * K[n][s].
// v2: s-dimension split 2-way ACROSS waves -> 256 blocks x 1024 threads
// (16 waves/CU = 4 waves/SIMD, was 2). The kernel is L2-latency-bound
// (K loads ~200cy L2 hits); doubling resident waves halves exposed latency.
// Per-lane: 16 K b128 loads (was 32), 128 FMAs. K L2 traffic unchanged:
// 256 blocks x 256 KB = 64 MB (each K element read once per block).
// Wave w: s-half h = w&1 (k-chunks 2h..2h+1), n-range [8*(w>>1), +8).
__global__ __launch_bounds__(1024, 4) void hippo_fused(const float* __restrict__ u,
                                                       const float* __restrict__ K,
                                                       float* __restrict__ out) {
    // 128 outputs x 128 lane-partials, +1 pad (stride 129 == 1 mod 32:
    // store conflict-free; tail read only 2-way aliased = free). 66 KB.
    __shared__ float red[128 * 129];

    const int tid   = threadIdx.x;
    const int rows0 = blockIdx.x * 2;     // 256 blocks x 2 rows = 512 rows
    const int w     = tid >> 6;           // wave 0..15
    const int l     = tid & 63;           // lane
    const int h     = w & 1;              // s-half: k-chunks {2h, 2h+1}
    const int n0    = (w >> 1) * 8;       // this wave-pair's n range

    // reversed-u fragments: ua[r][kk] = u[row][1020-256*(2h+kk)-4l .. +3]
    float4 ua[2][2];
    #pragma unroll
    for (int r = 0; r < 2; ++r) {
        const float* urow = u + (rows0 + r) * T_LEN;
        #pragma unroll
        for (int kk = 0; kk < 2; ++kk) {
            const int k = 2 * h + kk;
            ua[r][kk] = *(const float4*)(urow + (1020 - 256 * k - 4 * l));
        }
    }

    float acc[2][8];
    #pragma unroll
    for (int r = 0; r < 2; ++r)
        #pragma unroll
        for (int i = 0; i < 8; ++i) acc[r][i] = 0.f;

    const float4* K4 = (const float4*)K;  // row n = 256 float4
    #pragma unroll
    for (int i = 0; i < 8; ++i) {
        const int n = n0 + i;
        #pragma unroll
        for (int kk = 0; kk < 2; ++kk) {
            const float4 kv = K4[n * 256 + (2 * h + kk) * 64 + l];  // coalesced L2-hit
            #pragma unroll
            for (int r = 0; r < 2; ++r) {                 // reversal: c -> 3-c
                const float4 uv = ua[r][kk];
                acc[r][i] += kv.x * uv.w + kv.y * uv.z + kv.z * uv.y + kv.w * uv.x;
            }
        }
    }

    // cross-lane reduction: 128 partials per output (two half-waves)
    #pragma unroll
    for (int r = 0; r < 2; ++r)
        #pragma unroll
        for (int i = 0; i < 8; ++i)
            red[(r * 64 + n0 + i) * 129 + h * 64 + l] = acc[r][i];
    __syncthreads();

    if (tid < 128) {                       // tid = r*64 + n
        float s = 0.f;
        const float* p = &red[tid * 129];
        #pragma unroll 8
        for (int j = 0; j < 128; ++j) s += p[j];
        out[rows0 * 64 + tid] = s;         // 512 B contiguous store
    }
}

extern "C" void kernel_launch(void* const* d_in, const int* in_sizes, int n_in,
                              void* d_out, int out_size, void* d_ws, size_t ws_size,
                              hipStream_t stream) {
    const float* inputs = (const float*)d_in[0];   // (4,2,64,1024) fp32
    const float* K      = (const float*)d_in[1];   // (64,1024) fp32
    float* out = (float*)d_out;                    // (4,2,64,64) fp32

    hippo_fused<<<256, 1024, 0, stream>>>(inputs, K, out);
}

// Round 2
// 58.804 us; speedup vs baseline: 1.0441x; 1.0006x over previous
//
#include <hip/hip_runtime.h>

#define T_LEN 1024

// Fused single kernel. out[r][n] = sum_s u[r][1023-s] * K[n][s].
// v3: L2-channel de-hotspotting. All blocks previously walked K in lockstep;
// n-stride (4 KB) and wave-stride (32 KB) are channel-invariant under a
// 16ch x 256B interleave, so the whole XCD hit the same channel quarter at
// any instant. Fix: per-block phase rotation using bid>>3 (consecutive bids
// round-robin across XCDs, so bid&7 is constant per XCD -- must use bid>>3
// to vary WITHIN an XCD): flip the s-half assignment (+-2 KB phase) and
// rotate the n-visit order (+-4..28 KB phase). acc stays statically indexed
// (runtime-indexed reg arrays spill to scratch); rotation folds into the
// LDS store address. Tail reduction now two-stage over all 1024 threads.
__global__ __launch_bounds__(1024, 4) void hippo_fused(const float* __restrict__ u,
                                                       const float* __restrict__ K,
                                                       float* __restrict__ out) {
    __shared__ float red[128 * 129];   // 66 KB: 128 outputs x 128 partials, +1 pad
    __shared__ float red2[128 * 9];    // 4.5 KB: stage-2 partials, +1 pad

    const int tid   = threadIdx.x;
    const int bid   = blockIdx.x;
    const int rows0 = bid * 2;            // 256 blocks x 2 rows = 512 rows
    const int w     = tid >> 6;           // wave 0..15
    const int l     = tid & 63;           // lane
    const int rot   = bid >> 3;           // 0..31 within an XCD
    const int h     = (w ^ rot) & 1;      // s-half, phase-flipped per block
    const int n0    = (w >> 1) * 8;       // this wave-pair's n range

    // reversed-u fragments: ua[r][kk] = u[row][1020-256*(2h+kk)-4l .. +3]
    float4 ua[2][2];
    #pragma unroll
    for (int r = 0; r < 2; ++r) {
        const float* urow = u + (rows0 + r) * T_LEN;
        #pragma unroll
        for (int kk = 0; kk < 2; ++kk) {
            const int k = 2 * h + kk;
            ua[r][kk] = *(const float4*)(urow + (1020 - 256 * k - 4 * l));
        }
    }

    float acc[2][8];
    #pragma unroll
    for (int r = 0; r < 2; ++r)
        #pragma unroll
        for (int i = 0; i < 8; ++i) acc[r][i] = 0.f;

    const float4* K4 = (const float4*)K;  // row n = 256 float4
    #pragma unroll
    for (int ii = 0; ii < 8; ++ii) {
        const int n = n0 + ((ii + rot) & 7);          // rotated visit order
        #pragma unroll
        for (int kk = 0; kk < 2; ++kk) {
            const float4 kv = K4[n * 256 + (2 * h + kk) * 64 + l];  // coalesced L2-hit
            #pragma unroll
            for (int r = 0; r < 2; ++r) {             // reversal: c -> 3-c
                const float4 uv = ua[r][kk];
                acc[r][ii] += kv.x * uv.w + kv.y * uv.z + kv.z * uv.y + kv.w * uv.x;
            }
        }
    }

    // cross-lane reduction: 128 partials per output (two half-waves).
    // Fold the n-rotation back in here (address math, not register indexing).
    #pragma unroll
    for (int r = 0; r < 2; ++r)
        #pragma unroll
        for (int ii = 0; ii < 8; ++ii) {
            const int i = (ii + rot) & 7;
            red[(r * 64 + n0 + i) * 129 + h * 64 + l] = acc[r][ii];
        }
    __syncthreads();

    // stage A: 1024 threads, 16 adds each -> red2[128][8]
    {
        const int o   = tid >> 3;          // output 0..127
        const int seg = tid & 7;           // 16-element segment
        const float* p = &red[o * 129 + seg * 16];
        float s = 0.f;
        #pragma unroll
        for (int j = 0; j < 16; ++j) s += p[j];
        red2[o * 9 + seg] = s;
    }
    __syncthreads();

    // stage B: 128 threads, 8 adds each
    if (tid < 128) {                       // tid = r*64 + n
        const float* p = &red2[tid * 9];
        float s = 0.f;
        #pragma unroll
        for (int j = 0; j < 8; ++j) s += p[j];
        out[rows0 * 64 + tid] = s;         // 512 B contiguous store
    }
}

extern "C" void kernel_launch(void* const* d_in, const int* in_sizes, int n_in,
                              void* d_out, int out_size, void* d_ws, size_t ws_size,
                              hipStream_t stream) {
    const float* inputs = (const float*)d_in[0];   // (4,2,64,1024) fp32
    const float* K      = (const float*)d_in[1];   // (64,1024) fp32
    float* out = (float*)d_out;                    // (4,2,64,64) fp32

    hippo_fused<<<256, 1024, 0, stream>>>(inputs, K, out);
}